// Round 4
// baseline (272.900 us; speedup 1.0000x reference)
//
#include <hip/hip_runtime.h>

// MN neuron forward sim: T=1000 sequential steps, 64x512 independent chains.
// Round 6 structure: 2 chains/lane via packed FP32 + single self-pipelined wave.
//   - R4/R5 established: loads & barriers are NOT the bottleneck (depth-4
//     pipeline + store-drain removal + pinned batch all <=2% or regressed).
//     Bottleneck = consumer per-step issue (~35 instr * 2cyc) + exposed dep
//     chain with 1 wave/SIMD (VALUBusy 33% @ 189 cyc/step).
//   - Each lane now owns chains idx and idx+64: arithmetic done on float2
//     ext-vectors -> v_pk_{mul,add,max}_f32 on gfx950 (IEEE-identical per
//     half), ~26 packed instr cover 2 chain-steps; cmp/select stay scalar.
//     Two chains' dep chains hide each other where packing fails.
//   - No producer wave, no barriers: the single wave issues its own
//     global_load_lds (un-sinkable: no register result) 3 chunks ahead,
//     counted s_waitcnt vmcnt(20) = "chunk c+1 resident, c+2/c+3 in flight".
//   - NO asm register pins (R5 lesson: pins block per-step read pipelining).
// CORRECTNESS: binary spike output => bit-exact f32 vs numpy ref:
//   exact reference op order per chain, no FMA contraction (pragma applies to
//   vector ops too), selects for spike resets. Packed IEEE ops == scalar ops
//   per component.
// Pipeline ledger (outstanding global_load_lds, 10 issues/chunk):
//   prologue: issue 0,1,2 (30); wait vmcnt(20) -> chunk0 resident.
//   iter c<=46: compute c; issue c+3 (30 out); wait vmcnt(20) -> c+1 resident.
//   c=47: compute; wait vmcnt(10) -> 48 resident. c=48: wait vmcnt(0). c=49: -.
//   Buffer overwrite: issue(c+3) hits buf[(c-1)&3]; its ds_reads retired
//   during compute(c-1) (lgkmcnt-before-use), same-wave program order. Safe.

#define T_STEPS 1000
#define B_DIM 64
#define N_DIM 512
#define BN (B_DIM * N_DIM)   // 32768

#define K_CHUNK 20
#define NCHUNK (T_STEPS / K_CHUNK)   // 50
#define NBUF 4
#define CPB 128                      // chains per block (2 per lane)

// f32-rounded constants
#define C_DT   0.01f
#define C_EL   (-0.07f)
#define C_VR   (-0.07f)
#define C_TR   (-0.06f)
#define C_TINF (-0.05f)
#define C_B    12.77495288848877f
#define C_G    45.24007797241211f
#define C_K1   200.0f
#define C_K2   20.0f
#define C_R1   0.3858567178249359f
#define C_R2   (-1.1421641111373901f)

typedef const __attribute__((address_space(1))) void* gp_t;
typedef __attribute__((address_space(3))) void* lp_t;
typedef float v2f __attribute__((ext_vector_type(2)));

__device__ __forceinline__ v2f mn_step2(v2f xt, v2f lin, v2f av,
                                        v2f A1v, v2f A2v,
                                        v2f& V, v2f& i1, v2f& i2, v2f& Thr)
{
#pragma clang fp contract(off)
    // packed arithmetic: identical IEEE op sequence per component as the
    // verified scalar mn_step (v_pk_* f32 rounding == v_* f32 rounding)
    i1 = i1 - (C_K1 * i1) * C_DT;
    i2 = i2 - (C_K2 * i2) * C_DT;
    v2f p  = lin * xt;
    v2f q  = p + i1;
    v2f r  = q + i2;
    v2f e  = V - C_EL;
    v2f g  = C_G * e;
    v2f s  = r - g;
    v2f d  = C_DT * s;
    V = V + d;
    v2f e2 = V - C_EL;
    v2f u  = av * e2;
    v2f w  = Thr - C_TINF;
    v2f bw = C_B * w;
    v2f s2 = u - bw;
    v2f d2 = C_DT * s2;
    Thr = Thr + d2;
    v2f diff = V - Thr;
    v2f i1r = (C_R1 * i1) + A1v;   // computed from post-decay, pre-reset i1 (ref order)
    v2f i2r = (C_R2 * i2) + A2v;

    v2f spk;
    {   // chain 0 spike logic (cmp/select not packable)
        bool sb = diff.x > 0.0f;
        spk.x = sb ? 1.0f : 0.0f;
        i1.x  = sb ? i1r.x : i1.x;
        i2.x  = sb ? i2r.x : i2.x;
        float tm = fmaxf(Thr.x, C_TR);
        Thr.x = sb ? tm : Thr.x;
        V.x   = sb ? C_VR : V.x;
    }
    {   // chain 1 spike logic
        bool sb = diff.y > 0.0f;
        spk.y = sb ? 1.0f : 0.0f;
        i1.y  = sb ? i1r.y : i1.y;
        i2.y  = sb ? i2r.y : i2.y;
        float tm = fmaxf(Thr.y, C_TR);
        Thr.y = sb ? tm : Thr.y;
        V.y   = sb ? C_VR : V.y;
    }
    return spk;
}

__global__ __launch_bounds__(64) void mn_neuron_kernel(
    const float* __restrict__ x, const float* __restrict__ linear,
    const float* __restrict__ a, const float* __restrict__ A1,
    const float* __restrict__ A2, float* __restrict__ out)
{
#pragma clang fp contract(off)
    // lds[buf][t_in_chunk][chain_in_block]  (rows of 512B)
    __shared__ float lds[NBUF][K_CHUNK][CPB];   // 40960 B

    const int lane = threadIdx.x;          // 0..63
    const int blk  = blockIdx.x;           // 0..255
    const int base = blk * CPB;
    const int idx0 = base + lane;          // chain A
    const int idx1 = idx0 + 64;            // chain B

    // staging source: lane l covers 16B; lanes 0..31 -> row t, 32..63 -> row t+1
    const float* pl = x + (size_t)base + (size_t)(lane >> 5) * BN
                        + (size_t)(lane & 31) * 4;

    auto issue = [&](int k) {   // 10 x global_load_lds w=16 -> buf k&3 (2 rows each)
        const float* pc = pl + (size_t)(k * K_CHUNK) * BN;
        float* dst = &lds[k & (NBUF - 1)][0][0];
#pragma unroll
        for (int s = 0; s < K_CHUNK / 2; ++s) {
            __builtin_amdgcn_global_load_lds(
                (gp_t)(pc + (size_t)(2 * s) * BN),
                (lp_t)(dst + 2 * s * CPB), 16, 0, 0);
        }
    };

    // 3 chunks in flight before any compute
    issue(0); issue(1); issue(2);

    const int n0 = idx0 & (N_DIM - 1);
    const int n1 = idx1 & (N_DIM - 1);
    v2f lin = {linear[n0], linear[n1]};
    v2f av  = {a[n0],      a[n1]};
    v2f A1v = {A1[n0],     A1[n1]};
    v2f A2v = {A2[n0],     A2[n1]};

    v2f V   = {C_EL,   C_EL};
    v2f i1  = {0.0f,   0.0f};
    v2f i2  = {0.0f,   0.0f};
    v2f Thr = {C_TINF, C_TINF};

    float* op = out + idx0;

    asm volatile("s_waitcnt vmcnt(20)" ::: "memory");   // chunk 0 resident

    for (int c = 0; c < NCHUNK; ++c) {
        const float* src = &lds[c & (NBUF - 1)][0][lane];

#pragma unroll
        for (int j = 0; j < K_CHUNK; ++j) {
            // two ds_read_b32, imm offsets; compiler free to pipeline per-step
            v2f xt = {src[j * CPB], src[j * CPB + 64]};
            v2f spk = mn_step2(xt, lin, av, A1v, A2v, V, i1, i2, Thr);
            __builtin_nontemporal_store(spk.x, op);        // chain A
            __builtin_nontemporal_store(spk.y, op + 64);   // chain B (imm +256B)
            op += BN;
        }

        if (c + 3 < NCHUNK) {
            issue(c + 3);                                   // 30 outstanding
            asm volatile("s_waitcnt vmcnt(20)" ::: "memory"); // chunk c+1 resident
        } else if (c == NCHUNK - 3) {
            asm volatile("s_waitcnt vmcnt(10)" ::: "memory"); // chunk 48 resident
        } else if (c == NCHUNK - 2) {
            asm volatile("s_waitcnt vmcnt(0)" ::: "memory");  // chunk 49 resident
        }
    }
}

extern "C" void kernel_launch(void* const* d_in, const int* in_sizes, int n_in,
                              void* d_out, int out_size, void* d_ws, size_t ws_size,
                              hipStream_t stream) {
    const float* x      = (const float*)d_in[0];
    const float* linear = (const float*)d_in[1];
    const float* a      = (const float*)d_in[2];
    const float* A1     = (const float*)d_in[3];
    const float* A2     = (const float*)d_in[4];
    float* out = (float*)d_out;

    // 256 blocks x 64 threads: one self-pipelined wave per block, 2 chains/lane
    mn_neuron_kernel<<<BN / CPB, 64, 0, stream>>>(x, linear, a, A1, A2, out);
}

// Round 6
// 232.068 us; speedup vs baseline: 1.1759x; 1.1759x over previous
//
#include <hip/hip_runtime.h>

// MN neuron forward sim: T=1000 sequential steps, 64x512 independent chains.
// Round 7b: R4 producer/consumer base + issue-side cuts on the consumer wave.
//   (7a failed to compile: __builtin_nontemporal_store rejects HIP float4
//    class type; now uses clang ext_vector_type(4).)
// Established facts (R2-R6):
//   - wall time == one wave's serial 1000-step time (189k cyc = 78.8us; R6's
//     277k = 115us; R3's 281k = 117us). TLP/wave-count irrelevant.
//   - NOT LDS read latency (R5: pure-register compute -> 210 cyc/step).
//   - NOT store drains (R4), NOT producer RT (R5 depth-4 null).
//   - Remaining suspects: per-step issue overhead (literal-carrying VOP2s,
//     store addr arith, VMEM store) vs dependent-VALU latency floor.
// This round removes all issue overhead:
//   1. all 10 FP constants hoisted to SGPRs (asm-pinned) -> no literal dwords
//      in the hot loop.
//   2. consumer writes spikes to LDS (ds_write_b32 imm-offset, no addr math);
//      idle producer flushes them to HBM as dwordx4 NT stores (5/chunk).
//   3. s_setprio 1 on consumer (producer/consumer phase diversity).
// CORRECTNESS: binary spike output => bit-exact f32 vs numpy ref:
//   exact reference op order, no FMA contraction, selects for spike resets.
//   SGPR-held constants are bit-identical values; op sequence unchanged.
// Barrier ledger: both waves arrive 51x (B0 + 50). Spike double-buffer:
//   consumer writes sb[c&1] during chunk c, lgkmcnt(0) before B(c+1);
//   producer flushes sb[(c-1)&1] after B(c), lgkmcnt(0) before B(c+1);
//   consumer reuses sb[(c+1)&1]=sb[(c-1)&1] only after B(c+1). No race.
//   x double-buffer identical to verified R4 scheme.

#define T_STEPS 1000
#define B_DIM 64
#define N_DIM 512
#define BN (B_DIM * N_DIM)   // 32768

#define K_CHUNK 20
#define NCHUNK (T_STEPS / K_CHUNK)   // 50

typedef const __attribute__((address_space(1))) void* gp_t;
typedef __attribute__((address_space(3))) void* lp_t;
typedef float f32x4 __attribute__((ext_vector_type(4)));

__device__ __forceinline__ void raw_barrier() {
    // s_barrier WITHOUT the vmcnt(0)/lgkmcnt(0) drain __syncthreads() emits.
    asm volatile("s_barrier" ::: "memory");
}

struct Consts {
    float k200, k20, kDT, kEL, kG, kTINF, kB, kR1, kR2, kTR;
};

__device__ __forceinline__ float mn_step(float xt, float lin, float av,
                                         float A1v, float A2v, const Consts& K,
                                         float& V, float& i1, float& i2,
                                         float& Thr)
{
#pragma clang fp contract(off)
    // identical IEEE op order to the verified kernel; constants now SGPRs
    i1 = i1 - (K.k200 * i1) * K.kDT;
    i2 = i2 - (K.k20  * i2) * K.kDT;
    float p  = lin * xt;
    float q  = p + i1;
    float r  = q + i2;
    float e  = V - K.kEL;
    float g  = K.kG * e;
    float s  = r - g;
    float d  = K.kDT * s;
    V = V + d;
    float e2 = V - K.kEL;
    float u  = av * e2;
    float w  = Thr - K.kTINF;
    float bw = K.kB * w;
    float s2 = u - bw;
    float d2 = K.kDT * s2;
    Thr = Thr + d2;
    float diff = V - Thr;
    bool  sb   = diff > 0.0f;
    float spk  = sb ? 1.0f : 0.0f;          // inline consts, free
    float i1r = (K.kR1 * i1) + A1v;
    float i2r = (K.kR2 * i2) + A2v;
    i1  = sb ? i1r : i1;
    i2  = sb ? i2r : i2;
    float tm = fmaxf(Thr, K.kTR);
    Thr = sb ? tm : Thr;
    V   = sb ? K.kEL : V;                   // VR == EL == -0.07f (same bits)
    return spk;
}

__global__ __launch_bounds__(128) void mn_neuron_kernel(
    const float* __restrict__ x, const float* __restrict__ linear,
    const float* __restrict__ a, const float* __restrict__ A1,
    const float* __restrict__ A2, float* __restrict__ out)
{
#pragma clang fp contract(off)
    __shared__ float xb_buf[2][K_CHUNK][64];   // staged x
    __shared__ float sb_buf[2][K_CHUNK][64];   // staged spikes

    const int lane = threadIdx.x & 63;
    const int wid  = threadIdx.x >> 6;     // 0 = consumer, 1 = producer
    const int blk  = blockIdx.x;

    if (wid == 1) {
        // ---- producer: x staging + spike flush ----
        const float* pl = x + (size_t)(lane >> 4) * BN
                            + (size_t)blk * 64 + (size_t)(lane & 15) * 4;
        float* outp = out + (size_t)blk * 64;

        auto issue = [&](int k) {   // chunk k's 5 width-16 loads -> xb[k&1]
            const float* pc = pl + (size_t)(k * K_CHUNK) * BN;
            float* dst = &xb_buf[k & 1][0][0];
#pragma unroll
            for (int s5 = 0; s5 < K_CHUNK / 4; ++s5) {
                __builtin_amdgcn_global_load_lds(
                    (gp_t)(pc + (size_t)(s5 * 4) * BN),
                    (lp_t)(dst + s5 * 4 * 64), 16, 0, 0);
            }
        };

        const int r0 = lane >> 4;          // 0..3
        const int c4 = (lane & 15) * 4;    // 0,4,..,60
        auto flush = [&](int k) {          // spikes of chunk k -> HBM
            const int kb = k & 1;
#pragma unroll
            for (int pz = 0; pz < K_CHUNK / 4; ++pz) {
                const int row = pz * 4 + r0;
                const f32x4 v = *reinterpret_cast<const f32x4*>(
                    &sb_buf[kb][row][c4]);                       // ds_read_b128
                f32x4* dp = reinterpret_cast<f32x4*>(
                    outp + (size_t)(k * K_CHUNK + row) * BN + c4);
                __builtin_nontemporal_store(v, dp);              // dwordx4 nt
            }
        };

        issue(0);
        asm volatile("s_waitcnt vmcnt(0)" ::: "memory");
        raw_barrier();                                           // B0

        for (int c = 0; c < NCHUNK; ++c) {
            if (c + 1 < NCHUNK) issue(c + 1);
            if (c >= 1)         flush(c - 1);
            // loads resident + flush ds_reads retired before next barrier
            // (flush stores may stay in flight; data already in registers)
            asm volatile("s_waitcnt vmcnt(0) lgkmcnt(0)" ::: "memory");
            raw_barrier();                                       // B(c+1)
        }
        flush(NCHUNK - 1);   // after B50; consumer already exited
    } else {
        // ---- consumer: pure recurrence, zero global ops in the loop ----
        const int idx = blk * 64 + lane;       // b*N + n
        const int n   = idx & (N_DIM - 1);

        const float lin = linear[n];
        const float av  = a[n];
        const float A1v = A1[n];
        const float A2v = A2[n];

        Consts K = {200.0f, 20.0f, 0.01f, -0.07f,
                    45.24007797241211f, -0.05f, 12.77495288848877f,
                    0.3858567178249359f, -1.1421641111373901f, -0.06f};
        // pin every constant into an SGPR: no literal dwords in the hot loop
        asm volatile("" : "+s"(K.k200), "+s"(K.k20), "+s"(K.kDT),
                          "+s"(K.kEL), "+s"(K.kG), "+s"(K.kTINF),
                          "+s"(K.kB), "+s"(K.kR1), "+s"(K.kR2), "+s"(K.kTR));

        float V   = K.kEL;
        float i1  = 0.0f;
        float i2  = 0.0f;
        float Thr = K.kTINF;

        asm volatile("s_setprio 1" ::: "memory");
        raw_barrier();                                           // B0

        for (int c = 0; c < NCHUNK; ++c) {
            const float* src = &xb_buf[c & 1][0][lane];
            float*       dst = &sb_buf[c & 1][0][lane];
#pragma unroll
            for (int j = 0; j < K_CHUNK; ++j) {
                float xt  = src[j * 64];                 // ds_read_b32 imm
                float spk = mn_step(xt, lin, av, A1v, A2v, K, V, i1, i2, Thr);
                dst[j * 64] = spk;                       // ds_write_b32 imm
            }
            // spike writes visible to producer before it passes the barrier
            asm volatile("s_waitcnt lgkmcnt(0)" ::: "memory");
            raw_barrier();                                       // B(c+1)
        }
    }
}

extern "C" void kernel_launch(void* const* d_in, const int* in_sizes, int n_in,
                              void* d_out, int out_size, void* d_ws, size_t ws_size,
                              hipStream_t stream) {
    const float* x      = (const float*)d_in[0];
    const float* linear = (const float*)d_in[1];
    const float* a      = (const float*)d_in[2];
    const float* A1     = (const float*)d_in[3];
    const float* A2     = (const float*)d_in[4];
    float* out = (float*)d_out;

    // 512 blocks x 128 threads (1 consumer wave + 1 producer wave each)
    mn_neuron_kernel<<<BN / 64, 128, 0, stream>>>(x, linear, a, A1, A2, out);
}